// Round 1
// baseline (157.651 us; speedup 1.0000x reference)
//
#include <hip/hip_runtime.h>
#include <hip/hip_bf16.h>

// NLL of bivariate Gaussian, log-domain formulation.
// nll = z/(2(1-rho^2)) + log(2pi) + lsx + lsy + 0.5*log(1-rho^2)
// Clip: -log(max(pdf, 1e-10)) == fminf(nll, -log(1e-10)).
//
// R7: dual-path streaming. R0-R5 capped the VGPR-return read path at ~3.4 TB/s;
// R6 moved everything onto the TA->LDS DMA path and landed at the same ~3.4.
// Theory: the two return paths are throttled independently, so splitting the
// stream overlaps them: o (80 MiB, 62%) stays on global_load_lds DMA; y
// (48 MiB) moves to direct per-lane dwordx4 VGPR loads (each lane's 4 points
// = 48 B = three aligned v4; y[...,1..2] picked from registers, no LDS pass).
// Dropping y from LDS shrinks the double buffer 64->40 KB => 4 blocks/CU.
// Pipeline is an explicit 2-stage ping-pong with distinct register sets per
// half (a loop-carried ya=yb copy would make the compiler emit vmcnt(0) at
// the loop bottom and kill the prefetch overlap).

#define THREADS 256
#define PPT 4                // points per thread
#define TILE (THREADS * PPT) // 1024 points per block-tile; 256 per wave
#define MAXBLOCKS 1024       // 40 KB LDS/block -> 4 blocks/CU, all-resident grid

typedef float v4 __attribute__((ext_vector_type(4)));
typedef __attribute__((address_space(3))) v4 as3_v4;
typedef const __attribute__((address_space(1))) v4 as1_v4;

__device__ __forceinline__ float point_nll(float mux, float muy, float lsx,
                                           float lsy, float w, float y1, float y2) {
    const float LOG_2PI = 1.8378770664093453f;
    const float CLIP    = 23.025850929940457f; // -log(1e-10)
    float isx  = __expf(-lsx);
    float isy  = __expf(-lsy);
    float nx   = (y1 - mux) * isx;
    float ny   = (y2 - muy) * isy;
    // tanh(w) = 1 - 2/(exp(2w)+1); rcp-based (2% abs tolerance => plenty).
    float e2w  = __expf(2.0f * w);
    float corr = fmaf(-2.0f, __builtin_amdgcn_rcpf(e2w + 1.0f), 1.0f);
    float omr  = fmaf(-corr, corr, 1.0f);          // 1 - rho^2
    float z    = fmaf(nx, nx, ny * ny) - 2.0f * corr * nx * ny;
    float nll  = fmaf(z, 0.5f * __builtin_amdgcn_rcpf(omr),
                      fmaf(0.5f, __logf(omr), lsx + lsy + LOG_2PI));
    return fminf(nll, CLIP); // inf/NaN (omr->0) folds to CLIP, matching ref
}

__global__ __launch_bounds__(THREADS, 4) void nll_partial_kernel(
    const float* __restrict__ y, const float* __restrict__ o,
    float* __restrict__ partial, int N) {
    // Per-wave double buffer, o only: 320 v4 = 5 KB per buffer.
    __shared__ v4 lds[4][2][320]; // 40 KB -> 4 blocks/CU
    const int tid  = threadIdx.x;
    const int wave = tid >> 6;
    const int lane = tid & 63;
    const v4* o4 = (const v4*)o;
    const v4* y4 = (const v4*)y;

    const int nfull = N / TILE; // full tiles only in the pipeline
    const int step  = gridDim.x;
    float acc = 0.0f;

    // o: 5x dwordx4 DMA per wave per tile. LDS dest is wave-uniform base;
    // HW deposits at base + lane*16 == layout.
    auto issue_o = [&](int t, int b) {
        const v4* gob = o4 + (long long)t * 1280 + wave * 320 + lane;
        v4* ob = &lds[wave][b][0];
#pragma unroll
        for (int k = 0; k < 5; ++k)
            __builtin_amdgcn_global_load_lds((as1_v4*)(gob + k * 64),
                                             (as3_v4*)(ob + k * 64), 16, 0, 2 /*NT*/);
    };
    // y: 3x aligned dwordx4 per lane (48 B window = this lane's 4 points).
    auto load_y = [&](int t, v4& z0, v4& z1, v4& z2) {
        const v4* gy = y4 + (long long)t * 768 + wave * 192 + lane * 3;
        z0 = gy[0]; z1 = gy[1]; z2 = gy[2];
    };
    // Wait only for the CURRENT tile's 8 loads (5 DMA + 3 y); the prefetched
    // tile's 8 stay in flight. vmcnt retires in issue order, so vmcnt(8)
    // exactly drains the older tile.
    auto wait_cur = [&](bool pre) {
        if (pre) __builtin_amdgcn_s_waitcnt(0x0F78); // vmcnt(8), lgkm/exp no-wait
        else     __builtin_amdgcn_s_waitcnt(0x0F70); // vmcnt(0)
        asm volatile("" ::: "memory"); // pin LDS reads below the waitcnt
    };
    // y float picks per lane: f[3j+1], f[3j+2] for j=0..3 out of 12 floats.
    auto compute = [&](int b, v4 z0, v4 z1, v4 z2) {
        const float* fo = (const float*)&lds[wave][b][0] + lane * (PPT * 5);
        acc += point_nll(fo[0],  fo[1],  fo[2],  fo[3],  fo[4],  z0[1], z0[2]);
        acc += point_nll(fo[5],  fo[6],  fo[7],  fo[8],  fo[9],  z1[0], z1[1]);
        acc += point_nll(fo[10], fo[11], fo[12], fo[13], fo[14], z1[3], z2[0]);
        acc += point_nll(fo[15], fo[16], fo[17], fo[18], fo[19], z2[2], z2[3]);
    };

    int t = blockIdx.x;
    v4 ya0, ya1, ya2, yb0, yb1, yb2;
    if (t < nfull) { issue_o(t, 0); load_y(t, ya0, ya1, ya2); }
    while (t < nfull) {
        // half 1: prefetch t1 into {buf1, yb}, compute t from {buf0, ya}
        const int  t1   = t + step;
        const bool pre1 = t1 < nfull;
        if (pre1) { issue_o(t1, 1); load_y(t1, yb0, yb1, yb2); }
        wait_cur(pre1);
        compute(0, ya0, ya1, ya2);
        if (!pre1) break;

        // half 2: prefetch t2 into {buf0, ya}, compute t1 from {buf1, yb}
        const int  t2   = t1 + step;
        const bool pre2 = t2 < nfull;
        if (pre2) { issue_o(t2, 0); load_y(t2, ya0, ya1, ya2); }
        wait_cur(pre2);
        compute(1, yb0, yb1, yb2);
        if (!pre2) break;
        t = t2;
    }

    // Tail points (N % TILE; zero for the reference shape): direct loads.
    long long gid = (long long)blockIdx.x * THREADS + tid;
    for (long long i = (long long)nfull * TILE + gid; i < (long long)N;
         i += (long long)step * THREADS) {
        acc += point_nll(o[i * 5 + 0], o[i * 5 + 1], o[i * 5 + 2],
                         o[i * 5 + 3], o[i * 5 + 4],
                         y[i * 3 + 1], y[i * 3 + 2]);
    }

    // wave-64 reduce, then cross-wave via LDS
#pragma unroll
    for (int off = 32; off > 0; off >>= 1) acc += __shfl_down(acc, off, 64);
    __shared__ float ws[THREADS / 64];
    if (lane == 0) ws[wave] = acc;
    __syncthreads();
    if (tid == 0) {
        float s = 0.0f;
#pragma unroll
        for (int i = 0; i < THREADS / 64; ++i) s += ws[i];
        partial[blockIdx.x] = s;
    }
}

__global__ __launch_bounds__(THREADS) void nll_final_kernel(
    const float* __restrict__ partial, int nparts, float* __restrict__ out,
    float inv_p) {
    float acc = 0.0f;
    for (int i = threadIdx.x; i < nparts; i += THREADS) acc += partial[i];
#pragma unroll
    for (int off = 32; off > 0; off >>= 1) acc += __shfl_down(acc, off, 64);
    __shared__ float ws[THREADS / 64];
    if ((threadIdx.x & 63) == 0) ws[threadIdx.x >> 6] = acc;
    __syncthreads();
    if (threadIdx.x == 0) {
        float s = 0.0f;
#pragma unroll
        for (int i = 0; i < THREADS / 64; ++i) s += ws[i];
        out[0] = s * inv_p;
    }
}

extern "C" void kernel_launch(void* const* d_in, const int* in_sizes, int n_in,
                              void* d_out, int out_size, void* d_ws, size_t ws_size,
                              hipStream_t stream) {
    const float* y = (const float*)d_in[0]; // (B,T,P,3)
    const float* o = (const float*)d_in[1]; // (B,T,P,5)
    int N = in_sizes[1] / 5;                // B*T*P points
    int ntiles = (N + TILE - 1) / TILE;     // 4096 for the reference shape
    int blocks = ntiles < MAXBLOCKS ? ntiles : MAXBLOCKS;
    if (blocks < 1) blocks = 1;

    float* partial = (float*)d_ws;
    nll_partial_kernel<<<blocks, THREADS, 0, stream>>>(y, o, partial, N);
    // P = 512 (pdf.shape[2] in the reference); 1/512 is exact in fp32.
    nll_final_kernel<<<1, THREADS, 0, stream>>>(partial, blocks, (float*)d_out,
                                                1.0f / 512.0f);
}